// Round 4
// baseline (2260.474 us; speedup 1.0000x reference)
//
#include <hip/hip_runtime.h>
#include <hip/hip_bf16.h>

// GCN link prediction. Inputs fp32 + int32; OUTPUT fp32 (scores[1M] ++ embed[n*64]).
// Workspace ~51.7MB: dinv | P(n*64 f32) | R(n*64 f32).
// Layer1 (128-wide) chunked by 32 feats; h1 chunk fused straight into GEMM2 accumulation.

__global__ void deg_init_kernel(float* __restrict__ deg, int n) {
    int i = blockIdx.x * blockDim.x + threadIdx.x;
    if (i < n) deg[i] = 1.0f;  // self-loop
}

__global__ void deg_count_kernel(const int* __restrict__ dst, int E, float* __restrict__ deg) {
    int e = blockIdx.x * blockDim.x + threadIdx.x;
    if (e < E) atomicAdd(&deg[dst[e]], 1.0f);
}

__global__ void dinv_kernel(float* __restrict__ deg, int n) {
    int i = blockIdx.x * blockDim.x + threadIdx.x;
    if (i < n) deg[i] = rsqrtf(deg[i]);
}

// Out[n x CW] = In[n x FIN] @ W[:, c0:c0+CW];  W is FIN x FOUT row-major.
template<int FIN, int FOUT, int CW>
__global__ void gemm_chunk_kernel(const float* __restrict__ In, const float* __restrict__ W,
                                  float* __restrict__ Out, int n, int c0) {
    __shared__ float sW[FIN * CW];
    for (int i = threadIdx.x; i < FIN * CW; i += 256) {
        int k = i / CW, c = i % CW;
        sW[i] = W[k * FOUT + c0 + c];
    }
    __syncthreads();
    constexpr int RPB = 256 / CW;
    int r = blockIdx.x * RPB + threadIdx.x / CW;
    int c = threadIdx.x % CW;
    if (r >= n) return;
    const float* row = In + (size_t)r * FIN;
    float acc = 0.0f;
#pragma unroll 16
    for (int k = 0; k < FIN; ++k) acc = fmaf(row[k], sW[k * CW + c], acc);
    Out[(size_t)r * CW + c] = acc;
}

// agg[dst, f] += dinv[src]*dinv[dst]*xw[src, f]; self-loops are e in [E, E+n).
template<int F>  // power of 2
__global__ void scatter_kernel(const float* __restrict__ xw, const int* __restrict__ src,
                               const int* __restrict__ dst, int E, int n,
                               const float* __restrict__ dinv, float* __restrict__ agg) {
    constexpr int SH = (F == 32) ? 5 : 6;
    size_t idx = (size_t)blockIdx.x * blockDim.x + threadIdx.x;
    int e = (int)(idx >> SH);
    int f = (int)(idx & (F - 1));
    int tot = E + n;
    if (e >= tot) return;
    int s, d;
    if (e < E) { s = src[e]; d = dst[e]; }
    else { s = d = e - E; }
    atomicAdd(&agg[(size_t)d * F + f], dinv[s] * dinv[d] * xw[(size_t)s * F + f]);
}

// A2[n x 64] += relu(Bc[n x CW] + b1c[CW]) @ W2c[CW x 64]  (h1 chunk consumed, never stored)
template<int CW>
__global__ void fuse_relu_pgemm_kernel(const float* __restrict__ Bc, const float* __restrict__ b1c,
                                       const float* __restrict__ W2c, float* __restrict__ A2, int n) {
    __shared__ float sW[CW * 64];
    __shared__ float sb[CW];
    for (int i = threadIdx.x; i < CW * 64; i += 256) sW[i] = W2c[i];
    if (threadIdx.x < CW) sb[threadIdx.x] = b1c[threadIdx.x];
    __syncthreads();
    size_t idx = (size_t)blockIdx.x * 256 + threadIdx.x;
    int r = (int)(idx >> 6), c = (int)(idx & 63);
    if (r >= n) return;
    float acc = A2[(size_t)r * 64 + c];
#pragma unroll
    for (int k = 0; k < CW; ++k) {
        float hv = fmaxf(Bc[(size_t)r * CW + k] + sb[k], 0.0f);
        acc = fmaf(hv, sW[k * 64 + c], acc);
    }
    A2[(size_t)r * 64 + c] = acc;
}

// Out[n x 64] = In[n x 64] @ W[64 x 64]
__global__ void gemm64_kernel(const float* __restrict__ In, const float* __restrict__ W,
                              float* __restrict__ Out, int n) {
    __shared__ float sW[64 * 64];
    for (int i = threadIdx.x; i < 64 * 64; i += 256) sW[i] = W[i];
    __syncthreads();
    int r = blockIdx.x * 4 + threadIdx.x / 64;
    int c = threadIdx.x % 64;
    if (r >= n) return;
    const float* row = In + (size_t)r * 64;
    float acc = 0.0f;
#pragma unroll 16
    for (int k = 0; k < 64; ++k) acc = fmaf(row[k], sW[k * 64 + c], acc);
    Out[(size_t)r * 64 + c] = acc;
}

template<bool RELU, bool EMIT>
__global__ void bias_act64_kernel(float* __restrict__ buf, const float* __restrict__ b,
                                  int n, float* __restrict__ emit) {
    size_t idx = (size_t)blockIdx.x * blockDim.x + threadIdx.x;
    if (idx >= (size_t)n * 64) return;
    int c = (int)(idx & 63);
    float v = buf[idx] + b[c];
    if (RELU) v = fmaxf(v, 0.0f);
    buf[idx] = v;
    if (EMIT) emit[idx] = v;
}

// One wave per scored edge; 64 lanes = 64 feature dims, butterfly reduce.
__global__ void score_kernel(const float* __restrict__ h, const int* __restrict__ pos,
                             const int* __restrict__ neg, int Ep, int En,
                             float* __restrict__ out) {
    int wid = (int)(((size_t)blockIdx.x * blockDim.x + threadIdx.x) >> 6);
    int lane = threadIdx.x & 63;
    int tot = Ep + En;
    if (wid >= tot) return;
    int j, i;
    if (wid < Ep) { j = pos[wid]; i = pos[Ep + wid]; }
    else { int e = wid - Ep; j = neg[e]; i = neg[En + e]; }
    float v = h[(size_t)i * 64 + lane] * h[(size_t)j * 64 + lane];
#pragma unroll
    for (int o = 32; o > 0; o >>= 1) v += __shfl_xor(v, o);
    if (lane == 0) out[wid] = v;
}

extern "C" void kernel_launch(void* const* d_in, const int* in_sizes, int n_in,
                              void* d_out, int out_size, void* d_ws, size_t ws_size,
                              hipStream_t stream) {
    const float* x   = (const float*)d_in[0];
    const int* train = (const int*)d_in[1];
    const int* pos   = (const int*)d_in[2];
    const int* neg   = (const int*)d_in[3];
    const float* W1  = (const float*)d_in[4];
    const float* b1  = (const float*)d_in[5];
    const float* W2  = (const float*)d_in[6];
    const float* b2  = (const float*)d_in[7];
    const float* W3  = (const float*)d_in[8];
    const float* b3  = (const float*)d_in[9];

    const int n  = in_sizes[0] / 128;
    const int E  = in_sizes[1] / 2;
    const int Ep = in_sizes[2] / 2;
    const int En = in_sizes[3] / 2;
    const int totE = E + n;

    // Workspace layout (~51.7 MB): dinv | P (n*64 f32) | R (n*64 f32)
    float* dinv = (float*)d_ws;
    float* P = dinv + 131072;            // xw2 accumulator, later xw3
    float* R = P + (size_t)n * 64;       // layer1 chunk bufs (cA|cB), later B2/B3
    float* cA = R;                        // n*32
    float* cB = R + (size_t)n * 32;       // n*32

    float* out_scores = (float*)d_out;
    float* out_embed  = out_scores + (Ep + En);

    const int nb256 = (n + 255) / 256;

    deg_init_kernel<<<nb256, 256, 0, stream>>>(dinv, n);
    deg_count_kernel<<<(E + 255) / 256, 256, 0, stream>>>(train + E, E, dinv);
    dinv_kernel<<<nb256, 256, 0, stream>>>(dinv, n);

    // ---- Layer 1 (128-wide, 4 chunks of 32) fused into GEMM2 accumulation ----
    hipMemsetAsync(P, 0, (size_t)n * 64 * sizeof(float), stream);  // A2 = 0
    for (int c = 0; c < 4; ++c) {
        const int c0 = c * 32;
        gemm_chunk_kernel<128, 128, 32><<<(n + 7) / 8, 256, 0, stream>>>(x, W1, cA, n, c0);
        hipMemsetAsync(cB, 0, (size_t)n * 32 * sizeof(float), stream);
        scatter_kernel<32><<<(int)(((size_t)totE * 32 + 255) / 256), 256, 0, stream>>>(
            cA, train, train + E, E, n, dinv, cB);
        fuse_relu_pgemm_kernel<32><<<(int)(((size_t)n * 64 + 255) / 256), 256, 0, stream>>>(
            cB, b1 + c0, W2 + (size_t)c0 * 64, P, n);
    }
    // P = xw2 [n x 64]

    // ---- Layer 2 aggregate + bias/relu; emit embed ----
    float* B2 = R;
    hipMemsetAsync(B2, 0, (size_t)n * 64 * sizeof(float), stream);
    scatter_kernel<64><<<(int)(((size_t)totE * 64 + 255) / 256), 256, 0, stream>>>(
        P, train, train + E, E, n, dinv, B2);
    bias_act64_kernel<true, true><<<(int)(((size_t)n * 64 + 255) / 256), 256, 0, stream>>>(
        B2, b2, n, out_embed);
    // B2 = h2 [n x 64]

    // ---- Layer 3 ----
    gemm64_kernel<<<(n + 3) / 4, 256, 0, stream>>>(B2, W3, P, n);   // P = xw3
    hipMemsetAsync(B2, 0, (size_t)n * 64 * sizeof(float), stream);
    scatter_kernel<64><<<(int)(((size_t)totE * 64 + 255) / 256), 256, 0, stream>>>(
        P, train, train + E, E, n, dinv, B2);
    bias_act64_kernel<false, false><<<(int)(((size_t)n * 64 + 255) / 256), 256, 0, stream>>>(
        B2, b3, n, nullptr);
    // B2 = h3 [n x 64]

    // ---- Scores ----
    score_kernel<<<(int)(((size_t)(Ep + En) * 64 + 255) / 256), 256, 0, stream>>>(
        B2, pos, neg, Ep, En, out_scores);
}

// Round 5
// 1620.558 us; speedup vs baseline: 1.3949x; 1.3949x over previous
//
#include <hip/hip_runtime.h>
#include <hip/hip_bf16.h>

// GCN link prediction. Inputs fp32 + int32; OUTPUT fp32 (scores[1M] ++ embed[n*64]).
// CSR-gather formulation (no float atomics): build CSR by dst once, reuse for all
// 3 aggregations. Layer1: x@W1 -> fused {gather128, +b1, ReLU, matvec @W2} -> xw2.
// Workspace ~84.8MB (proven safe: round-2 ran 103MB uncorrupted).

__global__ void count_kernel(const int* __restrict__ dst, int E, int* __restrict__ count) {
    int e = blockIdx.x * blockDim.x + threadIdx.x;
    if (e < E) atomicAdd(&count[dst[e]], 1);
}

// Single-block exclusive scan over count[n]; emits row_ptr, cursor(=row_ptr copy),
// and dinv = rsqrt(count+1) (self-loop included in degree).
__global__ __launch_bounds__(1024) void scan_kernel(const int* __restrict__ count,
                                                    int* __restrict__ row_ptr,
                                                    int* __restrict__ cursor,
                                                    float* __restrict__ dinv,
                                                    int n, int nchunk) {
    __shared__ int part[1024];
    int t = threadIdx.x;
    int lo = t * nchunk, hi = min(lo + nchunk, n);
    int s = 0;
    for (int i = lo; i < hi; ++i) s += count[i];
    part[t] = s;
    __syncthreads();
    for (int o = 1; o < 1024; o <<= 1) {
        int a = part[t];
        int b = (t >= o) ? part[t - o] : 0;
        __syncthreads();
        part[t] = a + b;
        __syncthreads();
    }
    int run = (t > 0) ? part[t - 1] : 0;
    for (int i = lo; i < hi; ++i) {
        row_ptr[i] = run;
        cursor[i] = run;
        run += count[i];
        dinv[i] = rsqrtf((float)count[i] + 1.0f);
    }
    if (t == 0) row_ptr[n] = part[1023];
}

__global__ void fill_kernel(const int* __restrict__ src, const int* __restrict__ dst, int E,
                            int* __restrict__ cursor, int* __restrict__ col) {
    int e = blockIdx.x * blockDim.x + threadIdx.x;
    if (e < E) {
        int p = atomicAdd(&cursor[dst[e]], 1);
        col[p] = src[e];
    }
}

// Out[n x 128] = In[n x 128] @ W[128 x 128]; 64 rows/block, W in LDS (64KB).
__global__ __launch_bounds__(256) void gemm1_kernel(const float* __restrict__ In,
                                                    const float* __restrict__ W,
                                                    float* __restrict__ Out, int n) {
    __shared__ float sW[128 * 128];
    for (int i = threadIdx.x; i < 128 * 128; i += 256) sW[i] = W[i];
    __syncthreads();
    int c = threadIdx.x & 127;
    int rh = threadIdx.x >> 7;  // 0..1
    int rbase = blockIdx.x * 64;
    for (int j = 0; j < 32; ++j) {
        int r = rbase + rh * 32 + j;
        if (r >= n) return;
        const float* row = In + (size_t)r * 128;
        float acc = 0.0f;
#pragma unroll 16
        for (int k = 0; k < 128; ++k) acc = fmaf(row[k], sW[k * 128 + c], acc);
        Out[(size_t)r * 128 + c] = acc;
    }
}

// Fused: P[d,:] = ( relu( dd*(dd*xw1[d] + sum_{s in N(d)} dinv[s]*xw1[s]) + b1 ) ) @ W2
// One wave per dst row; lane covers feats {l, l+64}; W2 (32KB) in LDS; h1 row via LDS.
__global__ __launch_bounds__(256) void gather_l1_kernel(
    const float* __restrict__ xw1, const int* __restrict__ row_ptr,
    const int* __restrict__ col, const float* __restrict__ dinv,
    const float* __restrict__ b1, const float* __restrict__ W2,
    float* __restrict__ P, int n) {
    __shared__ float sW2[128 * 64];
    __shared__ float sh1[4][128];
    for (int i = threadIdx.x; i < 128 * 64; i += 256) sW2[i] = W2[i];
    __syncthreads();
    int w = threadIdx.x >> 6, l = threadIdx.x & 63;
    int d = blockIdx.x * 4 + w;
    if (d >= n) return;
    float dd = dinv[d];
    int p0 = row_ptr[d], p1 = row_ptr[d + 1];
    const float* xr = xw1 + (size_t)d * 128;
    float a0 = dd * xr[l], a1 = dd * xr[l + 64];
    for (int e = p0; e < p1; ++e) {
        int s = col[e];
        float ws = dinv[s];
        const float* xs = xw1 + (size_t)s * 128;
        a0 = fmaf(ws, xs[l], a0);
        a1 = fmaf(ws, xs[l + 64], a1);
    }
    a0 = fmaxf(fmaf(dd, a0, b1[l]), 0.0f);
    a1 = fmaxf(fmaf(dd, a1, b1[l + 64]), 0.0f);
    sh1[w][l] = a0;
    sh1[w][l + 64] = a1;   // same-wave LDS RAW: ordered by lgkmcnt, no barrier needed
    float acc = 0.0f;
#pragma unroll 16
    for (int k = 0; k < 128; ++k) acc = fmaf(sh1[w][k], sW2[k * 64 + l], acc);
    P[(size_t)d * 64 + l] = acc;
}

// out[d,:] = maybe_relu( dd*(dd*xw[d] + sum dinv[s]*xw[s]) + b );  optional emit copy.
template<bool RELU, bool EMIT>
__global__ __launch_bounds__(256) void gather64_kernel(
    const float* __restrict__ xw, const int* __restrict__ row_ptr,
    const int* __restrict__ col, const float* __restrict__ dinv,
    const float* __restrict__ b, float* __restrict__ out,
    float* __restrict__ emit, int n) {
    int w = threadIdx.x >> 6, l = threadIdx.x & 63;
    int d = blockIdx.x * 4 + w;
    if (d >= n) return;
    float dd = dinv[d];
    int p0 = row_ptr[d], p1 = row_ptr[d + 1];
    float a = dd * xw[(size_t)d * 64 + l];
    for (int e = p0; e < p1; ++e) {
        int s = col[e];
        a = fmaf(dinv[s], xw[(size_t)s * 64 + l], a);
    }
    float v = fmaf(dd, a, b[l]);
    if (RELU) v = fmaxf(v, 0.0f);
    out[(size_t)d * 64 + l] = v;
    if (EMIT) emit[(size_t)d * 64 + l] = v;
}

// Out[n x 64] = In[n x 64] @ W[64 x 64]; 16 rows/block.
__global__ __launch_bounds__(256) void gemm64_kernel(const float* __restrict__ In,
                                                     const float* __restrict__ W,
                                                     float* __restrict__ Out, int n) {
    __shared__ float sW[64 * 64];
    for (int i = threadIdx.x; i < 64 * 64; i += 256) sW[i] = W[i];
    __syncthreads();
    int c = threadIdx.x & 63;
    int rh = threadIdx.x >> 6;  // 0..3
    int rbase = blockIdx.x * 16;
    for (int j = 0; j < 4; ++j) {
        int r = rbase + rh * 4 + j;
        if (r >= n) return;
        const float* row = In + (size_t)r * 64;
        float acc = 0.0f;
#pragma unroll 16
        for (int k = 0; k < 64; ++k) acc = fmaf(row[k], sW[k * 64 + c], acc);
        Out[(size_t)r * 64 + c] = acc;
    }
}

// One wave per scored edge; 64 lanes = 64 feature dims, butterfly reduce.
__global__ void score_kernel(const float* __restrict__ h, const int* __restrict__ pos,
                             const int* __restrict__ neg, int Ep, int En,
                             float* __restrict__ out) {
    int wid = (int)(((size_t)blockIdx.x * blockDim.x + threadIdx.x) >> 6);
    int lane = threadIdx.x & 63;
    int tot = Ep + En;
    if (wid >= tot) return;
    int j, i;
    if (wid < Ep) { j = pos[wid]; i = pos[Ep + wid]; }
    else { int e = wid - Ep; j = neg[e]; i = neg[En + e]; }
    float v = h[(size_t)i * 64 + lane] * h[(size_t)j * 64 + lane];
#pragma unroll
    for (int o = 32; o > 0; o >>= 1) v += __shfl_xor(v, o);
    if (lane == 0) out[wid] = v;
}

extern "C" void kernel_launch(void* const* d_in, const int* in_sizes, int n_in,
                              void* d_out, int out_size, void* d_ws, size_t ws_size,
                              hipStream_t stream) {
    const float* x   = (const float*)d_in[0];
    const int* train = (const int*)d_in[1];
    const int* pos   = (const int*)d_in[2];
    const int* neg   = (const int*)d_in[3];
    const float* W1  = (const float*)d_in[4];
    const float* b1  = (const float*)d_in[5];
    const float* W2  = (const float*)d_in[6];
    const float* b2  = (const float*)d_in[7];
    const float* W3  = (const float*)d_in[8];
    const float* b3  = (const float*)d_in[9];

    const int n  = in_sizes[0] / 128;
    const int E  = in_sizes[1] / 2;
    const int Ep = in_sizes[2] / 2;
    const int En = in_sizes[3] / 2;

    // Workspace layout (~84.8 MB):
    int* count   = (int*)d_ws;             // n
    int* row_ptr = count + n;              // n+1
    int* cursor  = row_ptr + (n + 1);      // n
    int* col     = cursor + n;             // E
    float* dinv  = (float*)(col + E);      // n
    float* xw1   = dinv + n + 64;          // n*128 (B2/h2/h3 alias this region)
    float* P     = xw1 + (size_t)n * 128;  // n*64
    float* B2    = xw1;                    // reuse: free after gather_l1 consumed xw1

    float* out_scores = (float*)d_out;
    float* out_embed  = out_scores + (Ep + En);

    const int nb256 = (n + 255) / 256;
    const int eb256 = (E + 255) / 256;

    // ---- CSR build (by dst) + dinv ----
    hipMemsetAsync(count, 0, (size_t)n * sizeof(int), stream);
    count_kernel<<<eb256, 256, 0, stream>>>(train + E, E, count);
    scan_kernel<<<1, 1024, 0, stream>>>(count, row_ptr, cursor, dinv, n, (n + 1023) / 1024);
    fill_kernel<<<eb256, 256, 0, stream>>>(train, train + E, E, cursor, col);

    // ---- Layer 1 GEMM + fused {aggregate, bias, ReLU, @W2} ----
    gemm1_kernel<<<(n + 63) / 64, 256, 0, stream>>>(x, W1, xw1, n);
    gather_l1_kernel<<<(n + 3) / 4, 256, 0, stream>>>(xw1, row_ptr, col, dinv, b1, W2, P, n);
    // P = xw2 [n x 64]; xw1 region now free -> B2

    // ---- Layer 2 aggregate (+b2, ReLU), emit embed ----
    gather64_kernel<true, true><<<(n + 3) / 4, 256, 0, stream>>>(
        P, row_ptr, col, dinv, b2, B2, out_embed, n);
    // B2 = h2

    // ---- Layer 3 ----
    gemm64_kernel<<<(n + 15) / 16, 256, 0, stream>>>(B2, W3, P, n);  // P = xw3
    gather64_kernel<false, false><<<(n + 3) / 4, 256, 0, stream>>>(
        P, row_ptr, col, dinv, b3, B2, nullptr, n);
    // B2 = h3

    // ---- Scores ----
    score_kernel<<<(int)(((size_t)(Ep + En) * 64 + 255) / 256), 256, 0, stream>>>(
        B2, pos, neg, Ep, En, out_scores);
}

// Round 6
// 920.034 us; speedup vs baseline: 2.4569x; 1.7614x over previous
//
#include <hip/hip_runtime.h>
#include <hip/hip_bf16.h>

// GCN link prediction. Inputs fp32+int32; OUTPUT fp32 (scores[1M] ++ embed[n*64]).
// CSR gather + bf16 feature tables (fp32 math), register-tiled 4x4 GEMMs.
// Pipeline: gemm1(x@W1->xw1 bf16) -> gather128(->h1 bf16) -> gemmA(h1@W2->P bf16)
//           -> gather64(->h2 fp32 = embed out) -> gemmB(h2@W3->xw3 bf16)
//           -> gather64(->h3 fp32) -> score.

__device__ __forceinline__ float lo16f(uint32_t u) { uint32_t x = u << 16; float f; __builtin_memcpy(&f, &x, 4); return f; }
__device__ __forceinline__ float hi16f(uint32_t u) { uint32_t x = u & 0xffff0000u; float f; __builtin_memcpy(&f, &x, 4); return f; }
__device__ __forceinline__ float u16f(unsigned short u) { uint32_t x = (uint32_t)u << 16; float f; __builtin_memcpy(&f, &x, 4); return f; }
__device__ __forceinline__ uint32_t pk2(float a, float b) {
    union { __hip_bfloat162 h; uint32_t u; } cv;
    cv.h = __hip_bfloat162(__float2bfloat16(a), __float2bfloat16(b));
    return cv.u;
}

// ---------------- CSR build ----------------
__global__ void count_kernel(const int* __restrict__ dst, int E, int* __restrict__ count) {
    int e = blockIdx.x * blockDim.x + threadIdx.x;
    if (e < E) atomicAdd(&count[dst[e]], 1);
}

__global__ __launch_bounds__(1024) void scan_kernel(const int* __restrict__ count,
                                                    int* __restrict__ row_ptr,
                                                    int* __restrict__ cursor,
                                                    float* __restrict__ dinv,
                                                    int n, int nchunk) {
    __shared__ int part[1024];
    int t = threadIdx.x;
    int lo = t * nchunk, hi = min(lo + nchunk, n);
    int s = 0;
    for (int i = lo; i < hi; ++i) s += count[i];
    part[t] = s;
    __syncthreads();
    for (int o = 1; o < 1024; o <<= 1) {
        int a = part[t];
        int b = (t >= o) ? part[t - o] : 0;
        __syncthreads();
        part[t] = a + b;
        __syncthreads();
    }
    int run = (t > 0) ? part[t - 1] : 0;
    for (int i = lo; i < hi; ++i) {
        row_ptr[i] = run;
        cursor[i] = run;
        run += count[i];
        dinv[i] = rsqrtf((float)count[i] + 1.0f);
    }
    if (t == 0) row_ptr[n] = part[1023];
}

__global__ void fill_kernel(const int* __restrict__ src, const int* __restrict__ dst, int E,
                            const float* __restrict__ dinv,
                            int* __restrict__ cursor, int* __restrict__ col,
                            float* __restrict__ wcol) {
    int e = blockIdx.x * blockDim.x + threadIdx.x;
    if (e < E) {
        int s = src[e];
        int p = atomicAdd(&cursor[dst[e]], 1);
        col[p] = s;
        wcol[p] = dinv[s];
    }
}

// ---------------- GEMMs (4x4 register tile, K-chunked LDS) ----------------
#define FMA16(a, b, acc)                                                     \
    acc[0][0] = fmaf(a.x, b.x, acc[0][0]); acc[0][1] = fmaf(a.x, b.y, acc[0][1]); \
    acc[0][2] = fmaf(a.x, b.z, acc[0][2]); acc[0][3] = fmaf(a.x, b.w, acc[0][3]); \
    acc[1][0] = fmaf(a.y, b.x, acc[1][0]); acc[1][1] = fmaf(a.y, b.y, acc[1][1]); \
    acc[1][2] = fmaf(a.y, b.z, acc[1][2]); acc[1][3] = fmaf(a.y, b.w, acc[1][3]); \
    acc[2][0] = fmaf(a.z, b.x, acc[2][0]); acc[2][1] = fmaf(a.z, b.y, acc[2][1]); \
    acc[2][2] = fmaf(a.z, b.z, acc[2][2]); acc[2][3] = fmaf(a.z, b.w, acc[2][3]); \
    acc[3][0] = fmaf(a.w, b.x, acc[3][0]); acc[3][1] = fmaf(a.w, b.y, acc[3][1]); \
    acc[3][2] = fmaf(a.w, b.z, acc[3][2]); acc[3][3] = fmaf(a.w, b.w, acc[3][3]);

// xw1[n x 128] = x[n x 128] @ W1[128 x 128], bf16 out. Tile 32r x 128c.
__global__ __launch_bounds__(256) void gemm1_kernel(const float* __restrict__ In,
                                                    const float* __restrict__ W,
                                                    __hip_bfloat16* __restrict__ Out, int n) {
    __shared__ float sInT[32][32];   // [k][row]
    __shared__ float sW[32][128];
    int t = threadIdx.x;
    int tr = t >> 5, tc = t & 31;    // rows 4*tr, cols 4*tc
    int rbase = blockIdx.x * 32;
    float acc[4][4] = {};
    for (int kt = 0; kt < 128; kt += 32) {
        {
            int r = t >> 3, k4 = (t & 7) << 2;
            int gr = rbase + r;
            float4 v = make_float4(0.f, 0.f, 0.f, 0.f);
            if (gr < n) v = *(const float4*)&In[(size_t)gr * 128 + kt + k4];
            sInT[k4 + 0][r] = v.x; sInT[k4 + 1][r] = v.y;
            sInT[k4 + 2][r] = v.z; sInT[k4 + 3][r] = v.w;
        }
        {
            const float4* Wv = (const float4*)&W[(size_t)kt * 128];
            float4* sWv = (float4*)&sW[0][0];
            for (int i = t; i < 1024; i += 256) sWv[i] = Wv[i];
        }
        __syncthreads();
#pragma unroll
        for (int k = 0; k < 32; ++k) {
            float4 a = *(const float4*)&sInT[k][tr << 2];
            float4 b = *(const float4*)&sW[k][tc << 2];
            FMA16(a, b, acc)
        }
        __syncthreads();
    }
#pragma unroll
    for (int i = 0; i < 4; ++i) {
        int gr = rbase + (tr << 2) + i;
        if (gr < n) {
            uint2 pk;
            pk.x = pk2(acc[i][0], acc[i][1]);
            pk.y = pk2(acc[i][2], acc[i][3]);
            *(uint2*)((uint32_t*)Out + (size_t)gr * 64 + (tc << 1)) = pk;
        }
    }
}

// P[n x 64] = h1[n x 128](bf16) @ W2[128 x 64](f32), bf16 out. Tile 64r x 64c.
__global__ __launch_bounds__(256) void gemmA_kernel(const __hip_bfloat16* __restrict__ In,
                                                    const float* __restrict__ W,
                                                    __hip_bfloat16* __restrict__ Out, int n) {
    __shared__ float sInT[32][64];
    __shared__ float sW[32][64];
    int t = threadIdx.x;
    int tr = t >> 4, tc = t & 15;
    int rbase = blockIdx.x * 64;
    float acc[4][4] = {};
    const uint32_t* Inu = (const uint32_t*)In;  // 64 u32 per row
    for (int kt = 0; kt < 128; kt += 32) {
        for (int i = t; i < 1024; i += 256) {   // 64 rows x 16 u32
            int r = i >> 4, ku = i & 15;
            int gr = rbase + r;
            uint32_t u = (gr < n) ? Inu[(size_t)gr * 64 + (kt >> 1) + ku] : 0u;
            sInT[2 * ku][r] = lo16f(u);
            sInT[2 * ku + 1][r] = hi16f(u);
        }
        {
            const float4* Wv = (const float4*)&W[(size_t)kt * 64];
            float4* sWv = (float4*)&sW[0][0];
            for (int i = t; i < 512; i += 256) sWv[i] = Wv[i];
        }
        __syncthreads();
#pragma unroll
        for (int k = 0; k < 32; ++k) {
            float4 a = *(const float4*)&sInT[k][tr << 2];
            float4 b = *(const float4*)&sW[k][tc << 2];
            FMA16(a, b, acc)
        }
        __syncthreads();
    }
#pragma unroll
    for (int i = 0; i < 4; ++i) {
        int gr = rbase + (tr << 2) + i;
        if (gr < n) {
            uint2 pk;
            pk.x = pk2(acc[i][0], acc[i][1]);
            pk.y = pk2(acc[i][2], acc[i][3]);
            *(uint2*)((uint32_t*)Out + (size_t)gr * 32 + (tc << 1)) = pk;
        }
    }
}

// xw3[n x 64] = h2[n x 64](f32) @ W3[64 x 64](f32), bf16 out. Tile 64r x 64c.
__global__ __launch_bounds__(256) void gemmB_kernel(const float* __restrict__ In,
                                                    const float* __restrict__ W,
                                                    __hip_bfloat16* __restrict__ Out, int n) {
    __shared__ float sInT[32][64];
    __shared__ float sW[32][64];
    int t = threadIdx.x;
    int tr = t >> 4, tc = t & 15;
    int rbase = blockIdx.x * 64;
    float acc[4][4] = {};
    for (int kt = 0; kt < 64; kt += 32) {
        for (int i = t; i < 512; i += 256) {    // 64 rows x 8 float4
            int r = i >> 3, k4 = (i & 7) << 2;
            int gr = rbase + r;
            float4 v = make_float4(0.f, 0.f, 0.f, 0.f);
            if (gr < n) v = *(const float4*)&In[(size_t)gr * 64 + kt + k4];
            sInT[k4 + 0][r] = v.x; sInT[k4 + 1][r] = v.y;
            sInT[k4 + 2][r] = v.z; sInT[k4 + 3][r] = v.w;
        }
        {
            const float4* Wv = (const float4*)&W[(size_t)kt * 64];
            float4* sWv = (float4*)&sW[0][0];
            for (int i = t; i < 512; i += 256) sWv[i] = Wv[i];
        }
        __syncthreads();
#pragma unroll
        for (int k = 0; k < 32; ++k) {
            float4 a = *(const float4*)&sInT[k][tr << 2];
            float4 b = *(const float4*)&sW[k][tc << 2];
            FMA16(a, b, acc)
        }
        __syncthreads();
    }
#pragma unroll
    for (int i = 0; i < 4; ++i) {
        int gr = rbase + (tr << 2) + i;
        if (gr < n) {
            uint2 pk;
            pk.x = pk2(acc[i][0], acc[i][1]);
            pk.y = pk2(acc[i][2], acc[i][3]);
            *(uint2*)((uint32_t*)Out + (size_t)gr * 32 + (tc << 1)) = pk;
        }
    }
}

// ---------------- Gathers (one wave per dst row, unroll-4) ----------------
// h1[d] = relu(dd*(dd*xw1[d] + sum wcol*xw1[s]) + b1), bf16 in/out, 128-wide.
__global__ __launch_bounds__(256) void gather128_kernel(
    const __hip_bfloat16* __restrict__ xw, const int* __restrict__ row_ptr,
    const int* __restrict__ col, const float* __restrict__ wcol,
    const float* __restrict__ dinv, const float* __restrict__ b1,
    __hip_bfloat16* __restrict__ h1, int n) {
    int w = threadIdx.x >> 6, l = threadIdx.x & 63;
    int d = blockIdx.x * 4 + w;
    if (d >= n) return;
    float dd = dinv[d];
    int p0 = row_ptr[d], p1 = row_ptr[d + 1];
    const uint32_t* X = (const uint32_t*)xw;
    uint32_t v = X[(size_t)d * 64 + l];
    float a0 = dd * lo16f(v), a1 = dd * hi16f(v);
    int e = p0;
    for (; e + 4 <= p1; e += 4) {
        int s0 = col[e], s1 = col[e + 1], s2 = col[e + 2], s3 = col[e + 3];
        float w0 = wcol[e], w1 = wcol[e + 1], w2 = wcol[e + 2], w3 = wcol[e + 3];
        uint32_t v0 = X[(size_t)s0 * 64 + l];
        uint32_t v1 = X[(size_t)s1 * 64 + l];
        uint32_t v2 = X[(size_t)s2 * 64 + l];
        uint32_t v3 = X[(size_t)s3 * 64 + l];
        a0 = fmaf(w0, lo16f(v0), a0); a1 = fmaf(w0, hi16f(v0), a1);
        a0 = fmaf(w1, lo16f(v1), a0); a1 = fmaf(w1, hi16f(v1), a1);
        a0 = fmaf(w2, lo16f(v2), a0); a1 = fmaf(w2, hi16f(v2), a1);
        a0 = fmaf(w3, lo16f(v3), a0); a1 = fmaf(w3, hi16f(v3), a1);
    }
    for (; e < p1; ++e) {
        int s = col[e]; float ww = wcol[e];
        uint32_t vv = X[(size_t)s * 64 + l];
        a0 = fmaf(ww, lo16f(vv), a0); a1 = fmaf(ww, hi16f(vv), a1);
    }
    a0 = fmaxf(fmaf(dd, a0, b1[2 * l]), 0.0f);
    a1 = fmaxf(fmaf(dd, a1, b1[2 * l + 1]), 0.0f);
    ((uint32_t*)h1)[(size_t)d * 64 + l] = pk2(a0, a1);
}

// out[d] = maybe_relu(dd*(dd*xw[d] + sum wcol*xw[s]) + b), bf16 table -> fp32 out, 64-wide.
template<bool RELU>
__global__ __launch_bounds__(256) void gather64b_kernel(
    const __hip_bfloat16* __restrict__ xw, const int* __restrict__ row_ptr,
    const int* __restrict__ col, const float* __restrict__ wcol,
    const float* __restrict__ dinv, const float* __restrict__ b,
    float* __restrict__ out, int n) {
    int w = threadIdx.x >> 6, l = threadIdx.x & 63;
    int d = blockIdx.x * 4 + w;
    if (d >= n) return;
    float dd = dinv[d];
    int p0 = row_ptr[d], p1 = row_ptr[d + 1];
    const unsigned short* X = (const unsigned short*)xw;
    float a = dd * u16f(X[(size_t)d * 64 + l]);
    int e = p0;
    for (; e + 4 <= p1; e += 4) {
        int s0 = col[e], s1 = col[e + 1], s2 = col[e + 2], s3 = col[e + 3];
        float w0 = wcol[e], w1 = wcol[e + 1], w2 = wcol[e + 2], w3 = wcol[e + 3];
        unsigned short v0 = X[(size_t)s0 * 64 + l];
        unsigned short v1 = X[(size_t)s1 * 64 + l];
        unsigned short v2 = X[(size_t)s2 * 64 + l];
        unsigned short v3 = X[(size_t)s3 * 64 + l];
        a = fmaf(w0, u16f(v0), a);
        a = fmaf(w1, u16f(v1), a);
        a = fmaf(w2, u16f(v2), a);
        a = fmaf(w3, u16f(v3), a);
    }
    for (; e < p1; ++e) {
        a = fmaf(wcol[e], u16f(X[(size_t)col[e] * 64 + l]), a);
    }
    float r = fmaf(dd, a, b[l]);
    if (RELU) r = fmaxf(r, 0.0f);
    out[(size_t)d * 64 + l] = r;
}

// ---------------- Score ----------------
__global__ void score_kernel(const float* __restrict__ h, const int* __restrict__ pos,
                             const int* __restrict__ neg, int Ep, int En,
                             float* __restrict__ out) {
    int wid = (int)(((size_t)blockIdx.x * blockDim.x + threadIdx.x) >> 6);
    int lane = threadIdx.x & 63;
    int tot = Ep + En;
    if (wid >= tot) return;
    int j, i;
    if (wid < Ep) { j = pos[wid]; i = pos[Ep + wid]; }
    else { int e = wid - Ep; j = neg[e]; i = neg[En + e]; }
    float v = h[(size_t)i * 64 + lane] * h[(size_t)j * 64 + lane];
#pragma unroll
    for (int o = 32; o > 0; o >>= 1) v += __shfl_xor(v, o);
    if (lane == 0) out[wid] = v;
}

extern "C" void kernel_launch(void* const* d_in, const int* in_sizes, int n_in,
                              void* d_out, int out_size, void* d_ws, size_t ws_size,
                              hipStream_t stream) {
    const float* x   = (const float*)d_in[0];
    const int* train = (const int*)d_in[1];
    const int* pos   = (const int*)d_in[2];
    const int* neg   = (const int*)d_in[3];
    const float* W1  = (const float*)d_in[4];
    const float* b1  = (const float*)d_in[5];
    const float* W2  = (const float*)d_in[6];
    const float* b2  = (const float*)d_in[7];
    const float* W3  = (const float*)d_in[8];
    const float* b3  = (const float*)d_in[9];

    const int n  = in_sizes[0] / 128;
    const int E  = in_sizes[1] / 2;
    const int Ep = in_sizes[2] / 2;
    const int En = in_sizes[3] / 2;

    // Workspace (~78.5 MB)
    char* wp = (char*)d_ws;
    auto alloc = [&](size_t bytes) { char* r = wp; wp += (bytes + 255) & ~(size_t)255; return r; };
    int*   count   = (int*)alloc((size_t)n * 4);
    int*   row_ptr = (int*)alloc(((size_t)n + 1) * 4);
    int*   cursor  = (int*)alloc((size_t)n * 4);
    int*   col     = (int*)alloc((size_t)E * 4);
    float* wcol    = (float*)alloc((size_t)E * 4);
    float* dinv    = (float*)alloc((size_t)n * 4);
    __hip_bfloat16* xw1 = (__hip_bfloat16*)alloc((size_t)n * 128 * 2);  // later reused as h3(f32 n*64)
    __hip_bfloat16* h1  = (__hip_bfloat16*)alloc((size_t)n * 128 * 2);
    __hip_bfloat16* P   = (__hip_bfloat16*)alloc((size_t)n * 64 * 2);   // xw2, later xw3
    float* h3 = (float*)xw1;
    __hip_bfloat16* xw3 = P;

    float* out_scores = (float*)d_out;
    float* out_embed  = out_scores + (Ep + En);  // h2 lives here directly

    const int eb256 = (E + 255) / 256;

    // CSR build + norm coefficients
    hipMemsetAsync(count, 0, (size_t)n * sizeof(int), stream);
    count_kernel<<<eb256, 256, 0, stream>>>(train + E, E, count);
    scan_kernel<<<1, 1024, 0, stream>>>(count, row_ptr, cursor, dinv, n, (n + 1023) / 1024);
    fill_kernel<<<eb256, 256, 0, stream>>>(train, train + E, E, dinv, cursor, col, wcol);

    // Layer 1
    gemm1_kernel<<<(n + 31) / 32, 256, 0, stream>>>(x, W1, xw1, n);
    gather128_kernel<<<(n + 3) / 4, 256, 0, stream>>>(xw1, row_ptr, col, wcol, dinv, b1, h1, n);
    gemmA_kernel<<<(n + 63) / 64, 256, 0, stream>>>(h1, W2, P, n);

    // Layer 2 (h2 written straight into out_embed)
    gather64b_kernel<true><<<(n + 3) / 4, 256, 0, stream>>>(P, row_ptr, col, wcol, dinv, b2, out_embed, n);

    // Layer 3
    gemmB_kernel<<<(n + 63) / 64, 256, 0, stream>>>(out_embed, W3, xw3, n);
    gather64b_kernel<false><<<(n + 3) / 4, 256, 0, stream>>>(xw3, row_ptr, col, wcol, dinv, b3, h3, n);

    // Scores
    score_kernel<<<(int)(((size_t)(Ep + En) * 64 + 255) / 256), 256, 0, stream>>>(
        h3, pos, neg, Ep, En, out_scores);
}

// Round 7
// 682.271 us; speedup vs baseline: 3.3132x; 1.3485x over previous
//
#include <hip/hip_runtime.h>
#include <hip/hip_bf16.h>

// GCN link prediction. Inputs fp32+int32; OUTPUT fp32 (scores[1M] ++ embed[n*64]).
// CSR gather + bf16 feature tables (fp32 math), register-tiled 4x4 GEMMs,
// 3-phase device-wide scan for CSR row_ptr (was: single-block scan = 280us).

__device__ __forceinline__ float lo16f(uint32_t u) { uint32_t x = u << 16; float f; __builtin_memcpy(&f, &x, 4); return f; }
__device__ __forceinline__ float hi16f(uint32_t u) { uint32_t x = u & 0xffff0000u; float f; __builtin_memcpy(&f, &x, 4); return f; }
__device__ __forceinline__ float u16f(unsigned short u) { uint32_t x = (uint32_t)u << 16; float f; __builtin_memcpy(&f, &x, 4); return f; }
__device__ __forceinline__ uint32_t pk2(float a, float b) {
    union { __hip_bfloat162 h; uint32_t u; } cv;
    cv.h = __hip_bfloat162(__float2bfloat16(a), __float2bfloat16(b));
    return cv.u;
}

// ---------------- CSR build ----------------
__global__ void count_kernel(const int* __restrict__ dst, int E, int* __restrict__ count) {
    int e = blockIdx.x * blockDim.x + threadIdx.x;
    if (e < E) atomicAdd(&count[dst[e]], 1);
}

// Phase 1: per-block (1024 elems) sum of count -> partial[b]
__global__ __launch_bounds__(256) void scan_partial_kernel(const int* __restrict__ count, int n,
                                                           int* __restrict__ partial) {
    __shared__ int red[256];
    int t = threadIdx.x;
    int base = blockIdx.x * 1024 + t * 4;
    int s = 0;
#pragma unroll
    for (int i = 0; i < 4; ++i) {
        int idx = base + i;
        if (idx < n) s += count[idx];
    }
    red[t] = s;
    __syncthreads();
    for (int o = 128; o > 0; o >>= 1) {
        if (t < o) red[t] += red[t + o];
        __syncthreads();
    }
    if (t == 0) partial[blockIdx.x] = red[0];
}

// Phase 2: single small block scans partials (nb <= 256) -> exclusive offsets; row_ptr[n]=total.
__global__ __launch_bounds__(256) void scan_offsets_kernel(int* __restrict__ partial, int nb,
                                                           int* __restrict__ row_ptr, int n) {
    __shared__ int sc[256];
    int t = threadIdx.x;
    sc[t] = (t < nb) ? partial[t] : 0;
    __syncthreads();
    for (int o = 1; o < 256; o <<= 1) {
        int v = sc[t];
        int u = (t >= o) ? sc[t - o] : 0;
        __syncthreads();
        sc[t] = v + u;
        __syncthreads();
    }
    if (t < nb) partial[t] = (t > 0) ? sc[t - 1] : 0;  // exclusive
    if (t == 0) row_ptr[n] = sc[255];
}

// Phase 3: per-block exclusive scan + block offset -> row_ptr/cursor/dinv.
__global__ __launch_bounds__(256) void scan_write_kernel(const int* __restrict__ count, int n,
                                                         const int* __restrict__ partial,
                                                         int* __restrict__ row_ptr,
                                                         int* __restrict__ cursor,
                                                         float* __restrict__ dinv) {
    __shared__ int sc[256];
    int t = threadIdx.x;
    int base = blockIdx.x * 1024 + t * 4;
    int c[4];
    int s = 0;
#pragma unroll
    for (int i = 0; i < 4; ++i) {
        int idx = base + i;
        c[i] = (idx < n) ? count[idx] : 0;
        s += c[i];
    }
    sc[t] = s;
    __syncthreads();
    for (int o = 1; o < 256; o <<= 1) {
        int v = sc[t];
        int u = (t >= o) ? sc[t - o] : 0;
        __syncthreads();
        sc[t] = v + u;
        __syncthreads();
    }
    int run = partial[blockIdx.x] + ((t > 0) ? sc[t - 1] : 0);
#pragma unroll
    for (int i = 0; i < 4; ++i) {
        int idx = base + i;
        if (idx < n) {
            row_ptr[idx] = run;
            cursor[idx] = run;
            dinv[idx] = rsqrtf((float)c[i] + 1.0f);
            run += c[i];
        }
    }
}

__global__ void fill_kernel(const int* __restrict__ src, const int* __restrict__ dst, int E,
                            const float* __restrict__ dinv,
                            int* __restrict__ cursor, int* __restrict__ col,
                            float* __restrict__ wcol) {
    int e = blockIdx.x * blockDim.x + threadIdx.x;
    if (e < E) {
        int s = src[e];
        int p = atomicAdd(&cursor[dst[e]], 1);
        col[p] = s;
        wcol[p] = dinv[s];
    }
}

// ---------------- GEMMs (4x4 register tile, K-chunked LDS) ----------------
#define FMA16(a, b, acc)                                                     \
    acc[0][0] = fmaf(a.x, b.x, acc[0][0]); acc[0][1] = fmaf(a.x, b.y, acc[0][1]); \
    acc[0][2] = fmaf(a.x, b.z, acc[0][2]); acc[0][3] = fmaf(a.x, b.w, acc[0][3]); \
    acc[1][0] = fmaf(a.y, b.x, acc[1][0]); acc[1][1] = fmaf(a.y, b.y, acc[1][1]); \
    acc[1][2] = fmaf(a.y, b.z, acc[1][2]); acc[1][3] = fmaf(a.y, b.w, acc[1][3]); \
    acc[2][0] = fmaf(a.z, b.x, acc[2][0]); acc[2][1] = fmaf(a.z, b.y, acc[2][1]); \
    acc[2][2] = fmaf(a.z, b.z, acc[2][2]); acc[2][3] = fmaf(a.z, b.w, acc[2][3]); \
    acc[3][0] = fmaf(a.w, b.x, acc[3][0]); acc[3][1] = fmaf(a.w, b.y, acc[3][1]); \
    acc[3][2] = fmaf(a.w, b.z, acc[3][2]); acc[3][3] = fmaf(a.w, b.w, acc[3][3]);

// xw1[n x 128] = x[n x 128] @ W1[128 x 128], bf16 out. Tile 32r x 128c.
__global__ __launch_bounds__(256) void gemm1_kernel(const float* __restrict__ In,
                                                    const float* __restrict__ W,
                                                    __hip_bfloat16* __restrict__ Out, int n) {
    __shared__ float sInT[32][32];   // [k][row]
    __shared__ float sW[32][128];
    int t = threadIdx.x;
    int tr = t >> 5, tc = t & 31;    // rows 4*tr, cols 4*tc
    int rbase = blockIdx.x * 32;
    float acc[4][4] = {};
    for (int kt = 0; kt < 128; kt += 32) {
        {
            int r = t >> 3, k4 = (t & 7) << 2;
            int gr = rbase + r;
            float4 v = make_float4(0.f, 0.f, 0.f, 0.f);
            if (gr < n) v = *(const float4*)&In[(size_t)gr * 128 + kt + k4];
            sInT[k4 + 0][r] = v.x; sInT[k4 + 1][r] = v.y;
            sInT[k4 + 2][r] = v.z; sInT[k4 + 3][r] = v.w;
        }
        {
            const float4* Wv = (const float4*)&W[(size_t)kt * 128];
            float4* sWv = (float4*)&sW[0][0];
            for (int i = t; i < 1024; i += 256) sWv[i] = Wv[i];
        }
        __syncthreads();
#pragma unroll
        for (int k = 0; k < 32; ++k) {
            float4 a = *(const float4*)&sInT[k][tr << 2];
            float4 b = *(const float4*)&sW[k][tc << 2];
            FMA16(a, b, acc)
        }
        __syncthreads();
    }
#pragma unroll
    for (int i = 0; i < 4; ++i) {
        int gr = rbase + (tr << 2) + i;
        if (gr < n) {
            uint2 pk;
            pk.x = pk2(acc[i][0], acc[i][1]);
            pk.y = pk2(acc[i][2], acc[i][3]);
            *(uint2*)((uint32_t*)Out + (size_t)gr * 64 + (tc << 1)) = pk;
        }
    }
}

// P[n x 64] = h1[n x 128](bf16) @ W2[128 x 64](f32), bf16 out. Tile 64r x 64c.
__global__ __launch_bounds__(256) void gemmA_kernel(const __hip_bfloat16* __restrict__ In,
                                                    const float* __restrict__ W,
                                                    __hip_bfloat16* __restrict__ Out, int n) {
    __shared__ float sInT[32][64];
    __shared__ float sW[32][64];
    int t = threadIdx.x;
    int tr = t >> 4, tc = t & 15;
    int rbase = blockIdx.x * 64;
    float acc[4][4] = {};
    const uint32_t* Inu = (const uint32_t*)In;  // 64 u32 per row
    for (int kt = 0; kt < 128; kt += 32) {
        for (int i = t; i < 1024; i += 256) {   // 64 rows x 16 u32
            int r = i >> 4, ku = i & 15;
            int gr = rbase + r;
            uint32_t u = (gr < n) ? Inu[(size_t)gr * 64 + (kt >> 1) + ku] : 0u;
            sInT[2 * ku][r] = lo16f(u);
            sInT[2 * ku + 1][r] = hi16f(u);
        }
        {
            const float4* Wv = (const float4*)&W[(size_t)kt * 64];
            float4* sWv = (float4*)&sW[0][0];
            for (int i = t; i < 512; i += 256) sWv[i] = Wv[i];
        }
        __syncthreads();
#pragma unroll
        for (int k = 0; k < 32; ++k) {
            float4 a = *(const float4*)&sInT[k][tr << 2];
            float4 b = *(const float4*)&sW[k][tc << 2];
            FMA16(a, b, acc)
        }
        __syncthreads();
    }
#pragma unroll
    for (int i = 0; i < 4; ++i) {
        int gr = rbase + (tr << 2) + i;
        if (gr < n) {
            uint2 pk;
            pk.x = pk2(acc[i][0], acc[i][1]);
            pk.y = pk2(acc[i][2], acc[i][3]);
            *(uint2*)((uint32_t*)Out + (size_t)gr * 32 + (tc << 1)) = pk;
        }
    }
}

// xw3[n x 64] = h2[n x 64](f32) @ W3[64 x 64](f32), bf16 out. Tile 64r x 64c.
__global__ __launch_bounds__(256) void gemmB_kernel(const float* __restrict__ In,
                                                    const float* __restrict__ W,
                                                    __hip_bfloat16* __restrict__ Out, int n) {
    __shared__ float sInT[32][64];
    __shared__ float sW[32][64];
    int t = threadIdx.x;
    int tr = t >> 4, tc = t & 15;
    int rbase = blockIdx.x * 64;
    float acc[4][4] = {};
    for (int kt = 0; kt < 64; kt += 32) {
        for (int i = t; i < 512; i += 256) {    // 64 rows x 8 float4
            int r = i >> 3, k4 = (i & 7) << 2;
            int gr = rbase + r;
            float4 v = make_float4(0.f, 0.f, 0.f, 0.f);
            if (gr < n) v = *(const float4*)&In[(size_t)gr * 64 + kt + k4];
            sInT[k4 + 0][r] = v.x; sInT[k4 + 1][r] = v.y;
            sInT[k4 + 2][r] = v.z; sInT[k4 + 3][r] = v.w;
        }
        {
            const float4* Wv = (const float4*)&W[(size_t)kt * 64];
            float4* sWv = (float4*)&sW[0][0];
            for (int i = t; i < 512; i += 256) sWv[i] = Wv[i];
        }
        __syncthreads();
#pragma unroll
        for (int k = 0; k < 32; ++k) {
            float4 a = *(const float4*)&sInT[k][tr << 2];
            float4 b = *(const float4*)&sW[k][tc << 2];
            FMA16(a, b, acc)
        }
        __syncthreads();
    }
#pragma unroll
    for (int i = 0; i < 4; ++i) {
        int gr = rbase + (tr << 2) + i;
        if (gr < n) {
            uint2 pk;
            pk.x = pk2(acc[i][0], acc[i][1]);
            pk.y = pk2(acc[i][2], acc[i][3]);
            *(uint2*)((uint32_t*)Out + (size_t)gr * 32 + (tc << 1)) = pk;
        }
    }
}

// ---------------- Gathers (one wave per dst row, unroll-4) ----------------
__global__ __launch_bounds__(256) void gather128_kernel(
    const __hip_bfloat16* __restrict__ xw, const int* __restrict__ row_ptr,
    const int* __restrict__ col, const float* __restrict__ wcol,
    const float* __restrict__ dinv, const float* __restrict__ b1,
    __hip_bfloat16* __restrict__ h1, int n) {
    int w = threadIdx.x >> 6, l = threadIdx.x & 63;
    int d = blockIdx.x * 4 + w;
    if (d >= n) return;
    float dd = dinv[d];
    int p0 = row_ptr[d], p1 = row_ptr[d + 1];
    const uint32_t* X = (const uint32_t*)xw;
    uint32_t v = X[(size_t)d * 64 + l];
    float a0 = dd * lo16f(v), a1 = dd * hi16f(v);
    int e = p0;
    for (; e + 4 <= p1; e += 4) {
        int s0 = col[e], s1 = col[e + 1], s2 = col[e + 2], s3 = col[e + 3];
        float w0 = wcol[e], w1 = wcol[e + 1], w2 = wcol[e + 2], w3 = wcol[e + 3];
        uint32_t v0 = X[(size_t)s0 * 64 + l];
        uint32_t v1 = X[(size_t)s1 * 64 + l];
        uint32_t v2 = X[(size_t)s2 * 64 + l];
        uint32_t v3 = X[(size_t)s3 * 64 + l];
        a0 = fmaf(w0, lo16f(v0), a0); a1 = fmaf(w0, hi16f(v0), a1);
        a0 = fmaf(w1, lo16f(v1), a0); a1 = fmaf(w1, hi16f(v1), a1);
        a0 = fmaf(w2, lo16f(v2), a0); a1 = fmaf(w2, hi16f(v2), a1);
        a0 = fmaf(w3, lo16f(v3), a0); a1 = fmaf(w3, hi16f(v3), a1);
    }
    for (; e < p1; ++e) {
        int s = col[e]; float ww = wcol[e];
        uint32_t vv = X[(size_t)s * 64 + l];
        a0 = fmaf(ww, lo16f(vv), a0); a1 = fmaf(ww, hi16f(vv), a1);
    }
    a0 = fmaxf(fmaf(dd, a0, b1[2 * l]), 0.0f);
    a1 = fmaxf(fmaf(dd, a1, b1[2 * l + 1]), 0.0f);
    ((uint32_t*)h1)[(size_t)d * 64 + l] = pk2(a0, a1);
}

template<bool RELU>
__global__ __launch_bounds__(256) void gather64b_kernel(
    const __hip_bfloat16* __restrict__ xw, const int* __restrict__ row_ptr,
    const int* __restrict__ col, const float* __restrict__ wcol,
    const float* __restrict__ dinv, const float* __restrict__ b,
    float* __restrict__ out, int n) {
    int w = threadIdx.x >> 6, l = threadIdx.x & 63;
    int d = blockIdx.x * 4 + w;
    if (d >= n) return;
    float dd = dinv[d];
    int p0 = row_ptr[d], p1 = row_ptr[d + 1];
    const unsigned short* X = (const unsigned short*)xw;
    float a = dd * u16f(X[(size_t)d * 64 + l]);
    int e = p0;
    for (; e + 4 <= p1; e += 4) {
        int s0 = col[e], s1 = col[e + 1], s2 = col[e + 2], s3 = col[e + 3];
        float w0 = wcol[e], w1 = wcol[e + 1], w2 = wcol[e + 2], w3 = wcol[e + 3];
        unsigned short v0 = X[(size_t)s0 * 64 + l];
        unsigned short v1 = X[(size_t)s1 * 64 + l];
        unsigned short v2 = X[(size_t)s2 * 64 + l];
        unsigned short v3 = X[(size_t)s3 * 64 + l];
        a = fmaf(w0, u16f(v0), a);
        a = fmaf(w1, u16f(v1), a);
        a = fmaf(w2, u16f(v2), a);
        a = fmaf(w3, u16f(v3), a);
    }
    for (; e < p1; ++e) {
        a = fmaf(wcol[e], u16f(X[(size_t)col[e] * 64 + l]), a);
    }
    float r = fmaf(dd, a, b[l]);
    if (RELU) r = fmaxf(r, 0.0f);
    out[(size_t)d * 64 + l] = r;
}

// ---------------- Score ----------------
__global__ void score_kernel(const float* __restrict__ h, const int* __restrict__ pos,
                             const int* __restrict__ neg, int Ep, int En,
                             float* __restrict__ out) {
    int wid = (int)(((size_t)blockIdx.x * blockDim.x + threadIdx.x) >> 6);
    int lane = threadIdx.x & 63;
    int tot = Ep + En;
    if (wid >= tot) return;
    int j, i;
    if (wid < Ep) { j = pos[wid]; i = pos[Ep + wid]; }
    else { int e = wid - Ep; j = neg[e]; i = neg[En + e]; }
    float v = h[(size_t)i * 64 + lane] * h[(size_t)j * 64 + lane];
#pragma unroll
    for (int o = 32; o > 0; o >>= 1) v += __shfl_xor(v, o);
    if (lane == 0) out[wid] = v;
}

extern "C" void kernel_launch(void* const* d_in, const int* in_sizes, int n_in,
                              void* d_out, int out_size, void* d_ws, size_t ws_size,
                              hipStream_t stream) {
    const float* x   = (const float*)d_in[0];
    const int* train = (const int*)d_in[1];
    const int* pos   = (const int*)d_in[2];
    const int* neg   = (const int*)d_in[3];
    const float* W1  = (const float*)d_in[4];
    const float* b1  = (const float*)d_in[5];
    const float* W2  = (const float*)d_in[6];
    const float* b2  = (const float*)d_in[7];
    const float* W3  = (const float*)d_in[8];
    const float* b3  = (const float*)d_in[9];

    const int n  = in_sizes[0] / 128;
    const int E  = in_sizes[1] / 2;
    const int Ep = in_sizes[2] / 2;
    const int En = in_sizes[3] / 2;

    // Workspace (~78.6 MB)
    char* wp = (char*)d_ws;
    auto alloc = [&](size_t bytes) { char* r = wp; wp += (bytes + 255) & ~(size_t)255; return r; };
    int*   count   = (int*)alloc((size_t)n * 4);
    int*   row_ptr = (int*)alloc(((size_t)n + 1) * 4);
    int*   cursor  = (int*)alloc((size_t)n * 4);
    int*   partial = (int*)alloc(256 * 4);
    int*   col     = (int*)alloc((size_t)E * 4);
    float* wcol    = (float*)alloc((size_t)E * 4);
    float* dinv    = (float*)alloc((size_t)n * 4);
    __hip_bfloat16* xw1 = (__hip_bfloat16*)alloc((size_t)n * 128 * 2);  // reused as h3(f32 n*64)
    __hip_bfloat16* h1  = (__hip_bfloat16*)alloc((size_t)n * 128 * 2);
    __hip_bfloat16* P   = (__hip_bfloat16*)alloc((size_t)n * 64 * 2);   // xw2, later xw3
    float* h3 = (float*)xw1;
    __hip_bfloat16* xw3 = P;

    float* out_scores = (float*)d_out;
    float* out_embed  = out_scores + (Ep + En);  // h2 lives here directly

    const int eb256 = (E + 255) / 256;
    const int nbs = (n + 1023) / 1024;  // scan blocks (<=256 for n<=262144)

    // CSR build + norm coefficients
    hipMemsetAsync(count, 0, (size_t)n * sizeof(int), stream);
    count_kernel<<<eb256, 256, 0, stream>>>(train + E, E, count);
    scan_partial_kernel<<<nbs, 256, 0, stream>>>(count, n, partial);
    scan_offsets_kernel<<<1, 256, 0, stream>>>(partial, nbs, row_ptr, n);
    scan_write_kernel<<<nbs, 256, 0, stream>>>(count, n, partial, row_ptr, cursor, dinv);
    fill_kernel<<<eb256, 256, 0, stream>>>(train, train + E, E, dinv, cursor, col, wcol);

    // Layer 1
    gemm1_kernel<<<(n + 31) / 32, 256, 0, stream>>>(x, W1, xw1, n);
    gather128_kernel<<<(n + 3) / 4, 256, 0, stream>>>(xw1, row_ptr, col, wcol, dinv, b1, h1, n);
    gemmA_kernel<<<(n + 63) / 64, 256, 0, stream>>>(h1, W2, P, n);

    // Layer 2 (h2 written straight into out_embed)
    gather64b_kernel<true><<<(n + 3) / 4, 256, 0, stream>>>(P, row_ptr, col, wcol, dinv, b2, out_embed, n);

    // Layer 3
    gemmB_kernel<<<(n + 63) / 64, 256, 0, stream>>>(out_embed, W3, xw3, n);
    gather64b_kernel<false><<<(n + 3) / 4, 256, 0, stream>>>(xw3, row_ptr, col, wcol, dinv, b3, h3, n);

    // Scores
    score_kernel<<<(int)(((size_t)(Ep + En) * 64 + 255) / 256), 256, 0, stream>>>(
        h3, pos, neg, Ep, En, out_scores);
}

// Round 8
// 574.768 us; speedup vs baseline: 3.9328x; 1.1870x over previous
//
#include <hip/hip_runtime.h>
#include <hip/hip_bf16.h>

// GCN link prediction. Inputs fp32+int32; OUTPUT fp32 (scores[1M] ++ embed[n*64]).
// CSR gather + bf16 feature tables (fp32 math), register-tiled 4x4 GEMMs,
// device-wide scan, bf16 h3 + 2-edge-per-wave score (128B rows = 1 cache line).

__device__ __forceinline__ float lo16f(uint32_t u) { uint32_t x = u << 16; float f; __builtin_memcpy(&f, &x, 4); return f; }
__device__ __forceinline__ float hi16f(uint32_t u) { uint32_t x = u & 0xffff0000u; float f; __builtin_memcpy(&f, &x, 4); return f; }
__device__ __forceinline__ float u16f(unsigned short u) { uint32_t x = (uint32_t)u << 16; float f; __builtin_memcpy(&f, &x, 4); return f; }
__device__ __forceinline__ uint32_t pk2(float a, float b) {
    union { __hip_bfloat162 h; uint32_t u; } cv;
    cv.h = __hip_bfloat162(__float2bfloat16(a), __float2bfloat16(b));
    return cv.u;
}
__device__ __forceinline__ unsigned short bf16bits(float a) {
    union { __hip_bfloat16 b; unsigned short u; } cv;
    cv.b = __float2bfloat16(a);
    return cv.u;
}

// ---------------- CSR build ----------------
__global__ void count_kernel(const int* __restrict__ dst, int E, int* __restrict__ count) {
    int e = blockIdx.x * blockDim.x + threadIdx.x;
    if (e < E) atomicAdd(&count[dst[e]], 1);
}

__global__ __launch_bounds__(256) void scan_partial_kernel(const int* __restrict__ count, int n,
                                                           int* __restrict__ partial) {
    __shared__ int red[256];
    int t = threadIdx.x;
    int base = blockIdx.x * 1024 + t * 4;
    int s = 0;
#pragma unroll
    for (int i = 0; i < 4; ++i) {
        int idx = base + i;
        if (idx < n) s += count[idx];
    }
    red[t] = s;
    __syncthreads();
    for (int o = 128; o > 0; o >>= 1) {
        if (t < o) red[t] += red[t + o];
        __syncthreads();
    }
    if (t == 0) partial[blockIdx.x] = red[0];
}

__global__ __launch_bounds__(256) void scan_offsets_kernel(int* __restrict__ partial, int nb,
                                                           int* __restrict__ row_ptr, int n) {
    __shared__ int sc[256];
    int t = threadIdx.x;
    sc[t] = (t < nb) ? partial[t] : 0;
    __syncthreads();
    for (int o = 1; o < 256; o <<= 1) {
        int v = sc[t];
        int u = (t >= o) ? sc[t - o] : 0;
        __syncthreads();
        sc[t] = v + u;
        __syncthreads();
    }
    if (t < nb) partial[t] = (t > 0) ? sc[t - 1] : 0;  // exclusive
    if (t == 0) row_ptr[n] = sc[255];
}

__global__ __launch_bounds__(256) void scan_write_kernel(const int* __restrict__ count, int n,
                                                         const int* __restrict__ partial,
                                                         int* __restrict__ row_ptr,
                                                         int* __restrict__ cursor,
                                                         float* __restrict__ dinv) {
    __shared__ int sc[256];
    int t = threadIdx.x;
    int base = blockIdx.x * 1024 + t * 4;
    int c[4];
    int s = 0;
#pragma unroll
    for (int i = 0; i < 4; ++i) {
        int idx = base + i;
        c[i] = (idx < n) ? count[idx] : 0;
        s += c[i];
    }
    sc[t] = s;
    __syncthreads();
    for (int o = 1; o < 256; o <<= 1) {
        int v = sc[t];
        int u = (t >= o) ? sc[t - o] : 0;
        __syncthreads();
        sc[t] = v + u;
        __syncthreads();
    }
    int run = partial[blockIdx.x] + ((t > 0) ? sc[t - 1] : 0);
#pragma unroll
    for (int i = 0; i < 4; ++i) {
        int idx = base + i;
        if (idx < n) {
            row_ptr[idx] = run;
            cursor[idx] = run;
            dinv[idx] = rsqrtf((float)c[i] + 1.0f);
            run += c[i];
        }
    }
}

__global__ void fill_kernel(const int* __restrict__ src, const int* __restrict__ dst, int E,
                            const float* __restrict__ dinv,
                            int* __restrict__ cursor, int* __restrict__ col,
                            float* __restrict__ wcol) {
    int e = blockIdx.x * blockDim.x + threadIdx.x;
    if (e < E) {
        int s = src[e];
        int p = atomicAdd(&cursor[dst[e]], 1);
        col[p] = s;
        wcol[p] = dinv[s];
    }
}

// ---------------- GEMMs (4x4 register tile, K-chunked LDS) ----------------
#define FMA16(a, b, acc)                                                     \
    acc[0][0] = fmaf(a.x, b.x, acc[0][0]); acc[0][1] = fmaf(a.x, b.y, acc[0][1]); \
    acc[0][2] = fmaf(a.x, b.z, acc[0][2]); acc[0][3] = fmaf(a.x, b.w, acc[0][3]); \
    acc[1][0] = fmaf(a.y, b.x, acc[1][0]); acc[1][1] = fmaf(a.y, b.y, acc[1][1]); \
    acc[1][2] = fmaf(a.y, b.z, acc[1][2]); acc[1][3] = fmaf(a.y, b.w, acc[1][3]); \
    acc[2][0] = fmaf(a.z, b.x, acc[2][0]); acc[2][1] = fmaf(a.z, b.y, acc[2][1]); \
    acc[2][2] = fmaf(a.z, b.z, acc[2][2]); acc[2][3] = fmaf(a.z, b.w, acc[2][3]); \
    acc[3][0] = fmaf(a.w, b.x, acc[3][0]); acc[3][1] = fmaf(a.w, b.y, acc[3][1]); \
    acc[3][2] = fmaf(a.w, b.z, acc[3][2]); acc[3][3] = fmaf(a.w, b.w, acc[3][3]);

__global__ __launch_bounds__(256) void gemm1_kernel(const float* __restrict__ In,
                                                    const float* __restrict__ W,
                                                    __hip_bfloat16* __restrict__ Out, int n) {
    __shared__ float sInT[32][32];   // [k][row]
    __shared__ float sW[32][128];
    int t = threadIdx.x;
    int tr = t >> 5, tc = t & 31;
    int rbase = blockIdx.x * 32;
    float acc[4][4] = {};
    for (int kt = 0; kt < 128; kt += 32) {
        {
            int r = t >> 3, k4 = (t & 7) << 2;
            int gr = rbase + r;
            float4 v = make_float4(0.f, 0.f, 0.f, 0.f);
            if (gr < n) v = *(const float4*)&In[(size_t)gr * 128 + kt + k4];
            sInT[k4 + 0][r] = v.x; sInT[k4 + 1][r] = v.y;
            sInT[k4 + 2][r] = v.z; sInT[k4 + 3][r] = v.w;
        }
        {
            const float4* Wv = (const float4*)&W[(size_t)kt * 128];
            float4* sWv = (float4*)&sW[0][0];
            for (int i = t; i < 1024; i += 256) sWv[i] = Wv[i];
        }
        __syncthreads();
#pragma unroll
        for (int k = 0; k < 32; ++k) {
            float4 a = *(const float4*)&sInT[k][tr << 2];
            float4 b = *(const float4*)&sW[k][tc << 2];
            FMA16(a, b, acc)
        }
        __syncthreads();
    }
#pragma unroll
    for (int i = 0; i < 4; ++i) {
        int gr = rbase + (tr << 2) + i;
        if (gr < n) {
            uint2 pk;
            pk.x = pk2(acc[i][0], acc[i][1]);
            pk.y = pk2(acc[i][2], acc[i][3]);
            *(uint2*)((uint32_t*)Out + (size_t)gr * 64 + (tc << 1)) = pk;
        }
    }
}

__global__ __launch_bounds__(256) void gemmA_kernel(const __hip_bfloat16* __restrict__ In,
                                                    const float* __restrict__ W,
                                                    __hip_bfloat16* __restrict__ Out, int n) {
    __shared__ float sInT[32][64];
    __shared__ float sW[32][64];
    int t = threadIdx.x;
    int tr = t >> 4, tc = t & 15;
    int rbase = blockIdx.x * 64;
    float acc[4][4] = {};
    const uint32_t* Inu = (const uint32_t*)In;
    for (int kt = 0; kt < 128; kt += 32) {
        for (int i = t; i < 1024; i += 256) {
            int r = i >> 4, ku = i & 15;
            int gr = rbase + r;
            uint32_t u = (gr < n) ? Inu[(size_t)gr * 64 + (kt >> 1) + ku] : 0u;
            sInT[2 * ku][r] = lo16f(u);
            sInT[2 * ku + 1][r] = hi16f(u);
        }
        {
            const float4* Wv = (const float4*)&W[(size_t)kt * 64];
            float4* sWv = (float4*)&sW[0][0];
            for (int i = t; i < 512; i += 256) sWv[i] = Wv[i];
        }
        __syncthreads();
#pragma unroll
        for (int k = 0; k < 32; ++k) {
            float4 a = *(const float4*)&sInT[k][tr << 2];
            float4 b = *(const float4*)&sW[k][tc << 2];
            FMA16(a, b, acc)
        }
        __syncthreads();
    }
#pragma unroll
    for (int i = 0; i < 4; ++i) {
        int gr = rbase + (tr << 2) + i;
        if (gr < n) {
            uint2 pk;
            pk.x = pk2(acc[i][0], acc[i][1]);
            pk.y = pk2(acc[i][2], acc[i][3]);
            *(uint2*)((uint32_t*)Out + (size_t)gr * 32 + (tc << 1)) = pk;
        }
    }
}

__global__ __launch_bounds__(256) void gemmB_kernel(const float* __restrict__ In,
                                                    const float* __restrict__ W,
                                                    __hip_bfloat16* __restrict__ Out, int n) {
    __shared__ float sInT[32][64];
    __shared__ float sW[32][64];
    int t = threadIdx.x;
    int tr = t >> 4, tc = t & 15;
    int rbase = blockIdx.x * 64;
    float acc[4][4] = {};
    for (int kt = 0; kt < 64; kt += 32) {
        for (int i = t; i < 512; i += 256) {
            int r = i >> 3, k4 = (i & 7) << 2;
            int gr = rbase + r;
            float4 v = make_float4(0.f, 0.f, 0.f, 0.f);
            if (gr < n) v = *(const float4*)&In[(size_t)gr * 64 + kt + k4];
            sInT[k4 + 0][r] = v.x; sInT[k4 + 1][r] = v.y;
            sInT[k4 + 2][r] = v.z; sInT[k4 + 3][r] = v.w;
        }
        {
            const float4* Wv = (const float4*)&W[(size_t)kt * 64];
            float4* sWv = (float4*)&sW[0][0];
            for (int i = t; i < 512; i += 256) sWv[i] = Wv[i];
        }
        __syncthreads();
#pragma unroll
        for (int k = 0; k < 32; ++k) {
            float4 a = *(const float4*)&sInT[k][tr << 2];
            float4 b = *(const float4*)&sW[k][tc << 2];
            FMA16(a, b, acc)
        }
        __syncthreads();
    }
#pragma unroll
    for (int i = 0; i < 4; ++i) {
        int gr = rbase + (tr << 2) + i;
        if (gr < n) {
            uint2 pk;
            pk.x = pk2(acc[i][0], acc[i][1]);
            pk.y = pk2(acc[i][2], acc[i][3]);
            *(uint2*)((uint32_t*)Out + (size_t)gr * 32 + (tc << 1)) = pk;
        }
    }
}

// ---------------- Gathers (one wave per dst row, unroll-4) ----------------
__global__ __launch_bounds__(256) void gather128_kernel(
    const __hip_bfloat16* __restrict__ xw, const int* __restrict__ row_ptr,
    const int* __restrict__ col, const float* __restrict__ wcol,
    const float* __restrict__ dinv, const float* __restrict__ b1,
    __hip_bfloat16* __restrict__ h1, int n) {
    int w = threadIdx.x >> 6, l = threadIdx.x & 63;
    int d = blockIdx.x * 4 + w;
    if (d >= n) return;
    float dd = dinv[d];
    int p0 = row_ptr[d], p1 = row_ptr[d + 1];
    const uint32_t* X = (const uint32_t*)xw;
    uint32_t v = X[(size_t)d * 64 + l];
    float a0 = dd * lo16f(v), a1 = dd * hi16f(v);
    int e = p0;
    for (; e + 4 <= p1; e += 4) {
        int s0 = col[e], s1 = col[e + 1], s2 = col[e + 2], s3 = col[e + 3];
        float w0 = wcol[e], w1 = wcol[e + 1], w2 = wcol[e + 2], w3 = wcol[e + 3];
        uint32_t v0 = X[(size_t)s0 * 64 + l];
        uint32_t v1 = X[(size_t)s1 * 64 + l];
        uint32_t v2 = X[(size_t)s2 * 64 + l];
        uint32_t v3 = X[(size_t)s3 * 64 + l];
        a0 = fmaf(w0, lo16f(v0), a0); a1 = fmaf(w0, hi16f(v0), a1);
        a0 = fmaf(w1, lo16f(v1), a0); a1 = fmaf(w1, hi16f(v1), a1);
        a0 = fmaf(w2, lo16f(v2), a0); a1 = fmaf(w2, hi16f(v2), a1);
        a0 = fmaf(w3, lo16f(v3), a0); a1 = fmaf(w3, hi16f(v3), a1);
    }
    for (; e < p1; ++e) {
        int s = col[e]; float ww = wcol[e];
        uint32_t vv = X[(size_t)s * 64 + l];
        a0 = fmaf(ww, lo16f(vv), a0); a1 = fmaf(ww, hi16f(vv), a1);
    }
    a0 = fmaxf(fmaf(dd, a0, b1[2 * l]), 0.0f);
    a1 = fmaxf(fmaf(dd, a1, b1[2 * l + 1]), 0.0f);
    ((uint32_t*)h1)[(size_t)d * 64 + l] = pk2(a0, a1);
}

// OUT=0: fp32 out; OUT=1: bf16 out.
template<bool RELU, int OUT>
__global__ __launch_bounds__(256) void gather64b_kernel(
    const __hip_bfloat16* __restrict__ xw, const int* __restrict__ row_ptr,
    const int* __restrict__ col, const float* __restrict__ wcol,
    const float* __restrict__ dinv, const float* __restrict__ b,
    void* __restrict__ out, int n) {
    int w = threadIdx.x >> 6, l = threadIdx.x & 63;
    int d = blockIdx.x * 4 + w;
    if (d >= n) return;
    float dd = dinv[d];
    int p0 = row_ptr[d], p1 = row_ptr[d + 1];
    const unsigned short* X = (const unsigned short*)xw;
    float a = dd * u16f(X[(size_t)d * 64 + l]);
    int e = p0;
    for (; e + 4 <= p1; e += 4) {
        int s0 = col[e], s1 = col[e + 1], s2 = col[e + 2], s3 = col[e + 3];
        float w0 = wcol[e], w1 = wcol[e + 1], w2 = wcol[e + 2], w3 = wcol[e + 3];
        unsigned short v0 = X[(size_t)s0 * 64 + l];
        unsigned short v1 = X[(size_t)s1 * 64 + l];
        unsigned short v2 = X[(size_t)s2 * 64 + l];
        unsigned short v3 = X[(size_t)s3 * 64 + l];
        a = fmaf(w0, u16f(v0), a);
        a = fmaf(w1, u16f(v1), a);
        a = fmaf(w2, u16f(v2), a);
        a = fmaf(w3, u16f(v3), a);
    }
    for (; e < p1; ++e) {
        a = fmaf(wcol[e], u16f(X[(size_t)col[e] * 64 + l]), a);
    }
    float r = fmaf(dd, a, b[l]);
    if (RELU) r = fmaxf(r, 0.0f);
    if (OUT == 0) ((float*)out)[(size_t)d * 64 + l] = r;
    else ((unsigned short*)out)[(size_t)d * 64 + l] = bf16bits(r);
}

// ---------------- Score: 2 edges per wave, 32-lane groups, bf16 h3 (128B rows) ----
__global__ void score_kernel(const __hip_bfloat16* __restrict__ h, const int* __restrict__ pos,
                             const int* __restrict__ neg, int Ep, int En,
                             float* __restrict__ out) {
    int wid = (int)(((size_t)blockIdx.x * blockDim.x + threadIdx.x) >> 6);
    int lane = threadIdx.x & 63;
    int g = lane >> 5, sl = lane & 31;
    int ed = wid * 2 + g;
    int tot = Ep + En;
    if (ed >= tot) return;
    int j, i;
    if (ed < Ep) { j = pos[ed]; i = pos[Ep + ed]; }
    else { int e = ed - Ep; j = neg[e]; i = neg[En + e]; }
    const uint32_t* X = (const uint32_t*)h;
    uint32_t vi = X[(size_t)i * 32 + sl];
    uint32_t vj = X[(size_t)j * 32 + sl];
    float v = fmaf(hi16f(vi), hi16f(vj), lo16f(vi) * lo16f(vj));
#pragma unroll
    for (int o = 16; o > 0; o >>= 1) v += __shfl_xor(v, o);
    if (sl == 0) out[ed] = v;
}

extern "C" void kernel_launch(void* const* d_in, const int* in_sizes, int n_in,
                              void* d_out, int out_size, void* d_ws, size_t ws_size,
                              hipStream_t stream) {
    const float* x   = (const float*)d_in[0];
    const int* train = (const int*)d_in[1];
    const int* pos   = (const int*)d_in[2];
    const int* neg   = (const int*)d_in[3];
    const float* W1  = (const float*)d_in[4];
    const float* b1  = (const float*)d_in[5];
    const float* W2  = (const float*)d_in[6];
    const float* b2  = (const float*)d_in[7];
    const float* W3  = (const float*)d_in[8];
    const float* b3  = (const float*)d_in[9];

    const int n  = in_sizes[0] / 128;
    const int E  = in_sizes[1] / 2;
    const int Ep = in_sizes[2] / 2;
    const int En = in_sizes[3] / 2;

    // Workspace (~78.6 MB)
    char* wp = (char*)d_ws;
    auto alloc = [&](size_t bytes) { char* r = wp; wp += (bytes + 255) & ~(size_t)255; return r; };
    int*   count   = (int*)alloc((size_t)n * 4);
    int*   row_ptr = (int*)alloc(((size_t)n + 1) * 4);
    int*   cursor  = (int*)alloc((size_t)n * 4);
    int*   partial = (int*)alloc(256 * 4);
    int*   col     = (int*)alloc((size_t)E * 4);
    float* wcol    = (float*)alloc((size_t)E * 4);
    float* dinv    = (float*)alloc((size_t)n * 4);
    __hip_bfloat16* xw1 = (__hip_bfloat16*)alloc((size_t)n * 128 * 2);  // reused as h3(bf16 n*64)
    __hip_bfloat16* h1  = (__hip_bfloat16*)alloc((size_t)n * 128 * 2);
    __hip_bfloat16* P   = (__hip_bfloat16*)alloc((size_t)n * 64 * 2);   // xw2, later xw3
    __hip_bfloat16* h3  = xw1;   // bf16 reuse of xw1 region
    __hip_bfloat16* xw3 = P;

    float* out_scores = (float*)d_out;
    float* out_embed  = out_scores + (Ep + En);  // h2 lives here directly

    const int eb256 = (E + 255) / 256;
    const int nbs = (n + 1023) / 1024;

    // CSR build + norm coefficients
    hipMemsetAsync(count, 0, (size_t)n * sizeof(int), stream);
    count_kernel<<<eb256, 256, 0, stream>>>(train + E, E, count);
    scan_partial_kernel<<<nbs, 256, 0, stream>>>(count, n, partial);
    scan_offsets_kernel<<<1, 256, 0, stream>>>(partial, nbs, row_ptr, n);
    scan_write_kernel<<<nbs, 256, 0, stream>>>(count, n, partial, row_ptr, cursor, dinv);
    fill_kernel<<<eb256, 256, 0, stream>>>(train, train + E, E, dinv, cursor, col, wcol);

    // Layer 1
    gemm1_kernel<<<(n + 31) / 32, 256, 0, stream>>>(x, W1, xw1, n);
    gather128_kernel<<<(n + 3) / 4, 256, 0, stream>>>(xw1, row_ptr, col, wcol, dinv, b1, h1, n);
    gemmA_kernel<<<(n + 63) / 64, 256, 0, stream>>>(h1, W2, P, n);

    // Layer 2 (h2 written straight into out_embed, fp32)
    gather64b_kernel<true, 0><<<(n + 3) / 4, 256, 0, stream>>>(
        P, row_ptr, col, wcol, dinv, b2, out_embed, n);

    // Layer 3 (h3 emitted bf16 for the score stage)
    gemmB_kernel<<<(n + 63) / 64, 256, 0, stream>>>(out_embed, W3, xw3, n);
    gather64b_kernel<false, 1><<<(n + 3) / 4, 256, 0, stream>>>(
        xw3, row_ptr, col, wcol, dinv, b3, h3, n);

    // Scores: 2 edges per wave
    {
        int waves = (Ep + En + 1) / 2;
        score_kernel<<<(int)(((size_t)waves * 64 + 255) / 256), 256, 0, stream>>>(
            h3, pos, neg, Ep, En, out_scores);
    }
}